// Round 6
// baseline (94.066 us; speedup 1.0000x reference)
//
#include <hip/hip_runtime.h>
#include <hip/hip_fp16.h>
#include <math.h>

// LDR toep_corner via FFT chain. out[j,b] = Re ifft( sum_{i,s} Gf . fft( D . fft( Hf . Xf ) ) )
// Hf = fft(D.H), Xf = ifft(conj(D).x), Gf = fft(G), D_k = exp(i*pi*k/N).
//
// R19 = R18 (93.9us; paired mid, no spill) with mid's FFT re-factored
// radix-16x3 -> RADIX-8x4, 512 threads x 8 elems/thread:
//  * Diagnosis (R17 counters): mid is latency-bound (VALUBusy 18%, Occ 19%)
//    at 2 waves/SIMD; launch_bounds caps below the 16-elem FFT's ~170 VGPR
//    natural demand always spill (R14/R15). Fix: HALVE per-thread state.
//  * Paired radix-8 live set: v0[8]+v1[8]=32 VGPR + dft8 temps ~16 ->
//    natural demand ~100-125 < 128 boundary -> 16 waves/CU (4/SIMD, 2x)
//    WITHOUT any cap ((512,2) = cap 256, loosest).
//  * Radix-8 also cuts VALU/elem ~40% and shortens per-stage dep chains.
//    Cost: 6 barriers/FFT vs 4 — hidden by 2x waves.
//  * Stockham derivation (same framework as proven radix-16 core):
//    stage twiddles W_N^{t.k}, W_512^{(t>>3)k}, W_64^{(t>>6)k};
//    shuffles 8t+k -> t+512r; (t&7)+8k+64(t>>3); (t&63)+64k+512(t>>6);
//    output v[k] = X[tid + 512k]. Mirror: upper half = k in 4..7,
//    Nyquist (e=2048) = v[4] at tid 0.
//  * pre/fin unchanged (blast-radius control; radix-16, 256 thr).
// Fixed cost: ~44us harness fill of 256MB d_ws + restore, not controllable.

#define NFFT  4096
#define NT    256
#define NTM   512
#define CIN   4
#define COUT  4
#define RANK  4
#define BATCH 32
#define PI_F  3.14159265358979323846f

// cos/sin(pi*k/16), k=0..15 (pre kernel D-twiddles).
constexpr float CP16[16] = {
    1.0000000000000000f,  0.9807852804032304f,  0.9238795325112867f,  0.8314696123025452f,
    0.7071067811865476f,  0.5555702330196022f,  0.3826834323650898f,  0.1950903220161282f,
    0.0000000000000000f, -0.1950903220161282f, -0.3826834323650898f, -0.5555702330196022f,
   -0.7071067811865476f, -0.8314696123025452f, -0.9238795325112867f, -0.9807852804032304f };
constexpr float SP16[16] = {
    0.0000000000000000f,  0.1950903220161282f,  0.3826834323650898f,  0.5555702330196022f,
    0.7071067811865476f,  0.8314696123025452f,  0.9238795325112867f,  0.9807852804032304f,
    1.0000000000000000f,  0.9807852804032304f,  0.9238795325112867f,  0.8314696123025452f,
    0.7071067811865476f,  0.5555702330196022f,  0.3826834323650898f,  0.1950903220161282f };
// cos/sin(pi*k/8), k=0..7 (mid D-twiddle at 512 threads: e = tid + 512k).
constexpr float CP8[8] = {
    1.0000000000000000f,  0.9238795325112867f,  0.7071067811865476f,  0.3826834323650898f,
    0.0000000000000000f, -0.3826834323650898f, -0.7071067811865476f, -0.9238795325112867f };
constexpr float SP8[8] = {
    0.0000000000000000f,  0.3826834323650898f,  0.7071067811865476f,  0.9238795325112867f,
    1.0000000000000000f,  0.9238795325112867f,  0.7071067811865476f,  0.3826834323650898f };

__device__ __forceinline__ float2 cmul(float2 a, float2 b) {
    return make_float2(a.x*b.x - a.y*b.y, a.x*b.y + a.y*b.x);
}
__device__ __forceinline__ float2 cadd(float2 a, float2 b){ return make_float2(a.x+b.x, a.y+b.y); }
__device__ __forceinline__ float2 csub(float2 a, float2 b){ return make_float2(a.x-b.x, a.y-b.y); }

// LDS bank swizzle (R2-proven on radix-16 patterns; radix-8 patterns analyzed
// to ~4 lanes per 8B bank-slot = the 512B/wave floor).
__device__ __forceinline__ int SW(int e){ return e ^ ((e >> 4) & 15); }

// ---------------- radix-16 core (pre/fin, unchanged, R2-proven) -------------
template<int SIGN>
__device__ __forceinline__ void dft16(float2 v[16]) {
    const float sgn = (float)SIGN;
    const float C8 = 0.923879532511287f, S8 = 0.382683432365090f, H2 = 0.707106781186548f;
    const float2 w1 = make_float2( C8,  sgn*S8);
    const float2 w2 = make_float2( H2,  sgn*H2);
    const float2 w3 = make_float2( S8,  sgn*C8);
    const float2 w4 = make_float2(0.f,  sgn);
    const float2 w6 = make_float2(-H2,  sgn*H2);
    const float2 w9 = make_float2(-C8, -sgn*S8);
    float2 t[16];
    #pragma unroll
    for (int p = 0; p < 4; ++p) {
        float2 a0 = v[p], a1 = v[p+4], a2 = v[p+8], a3 = v[p+12];
        float2 b0 = cadd(a0,a2), b1 = csub(a0,a2), b2 = cadd(a1,a3), b3 = csub(a1,a3);
        float2 ib3 = make_float2(-sgn*b3.y, sgn*b3.x);   // SIGN*i*b3
        float2 X0 = cadd(b0,b2), X2c = csub(b0,b2);
        float2 X1 = cadd(b1,ib3), X3 = csub(b1,ib3);
        if (p == 1) { X1 = cmul(X1,w1); X2c = cmul(X2c,w2); X3 = cmul(X3,w3); }
        else if (p == 2) { X1 = cmul(X1,w2); X2c = cmul(X2c,w4); X3 = cmul(X3,w6); }
        else if (p == 3) { X1 = cmul(X1,w3); X2c = cmul(X2c,w6); X3 = cmul(X3,w9); }
        t[4*p+0]=X0; t[4*p+1]=X1; t[4*p+2]=X2c; t[4*p+3]=X3;
    }
    #pragma unroll
    for (int q = 0; q < 4; ++q) {
        float2 a0 = t[q], a1 = t[q+4], a2 = t[q+8], a3 = t[q+12];
        float2 b0 = cadd(a0,a2), b1 = csub(a0,a2), b2 = cadd(a1,a3), b3 = csub(a1,a3);
        float2 ib3 = make_float2(-sgn*b3.y, sgn*b3.x);
        v[q+0]  = cadd(b0,b2);
        v[q+8]  = csub(b0,b2);
        v[q+4]  = cadd(b1,ib3);
        v[q+12] = csub(b1,ib3);
    }
}

__device__ __forceinline__ void twiddle16(float2 v[16], float ang) {
    float sn, cs; __sincosf(ang, &sn, &cs);
    float2 w  = make_float2(cs, sn);
    float2 w2 = cmul(w, w);
    float2 to = w;   // odd powers
    float2 te = w2;  // even powers
    v[1] = cmul(v[1], to);
    v[2] = cmul(v[2], te);
    #pragma unroll
    for (int k = 3; k < 16; k += 2) {
        to = cmul(to, w2); v[k] = cmul(v[k], to);
        if (k + 1 < 16) { te = cmul(te, w2); v[k+1] = cmul(v[k+1], te); }
    }
}

template<int SIGN>
__device__ void fft4096_r16(float2 v[16], float2* lds, int tid) {
    dft16<SIGN>(v);
    twiddle16(v, (float)SIGN * 2.0f * PI_F * (float)tid / 4096.0f);
    #pragma unroll
    for (int k = 0; k < 16; ++k) lds[SW(16*tid + k)] = v[k];
    __syncthreads();
    #pragma unroll
    for (int r = 0; r < 16; ++r) v[r] = lds[SW(tid + 256*r)];
    dft16<SIGN>(v);
    twiddle16(v, (float)SIGN * 2.0f * PI_F * (float)(tid >> 4) / 256.0f);
    __syncthreads();                       // in-place: all reads before any write
    {
        const int q = tid & 15, p = tid >> 4;
        #pragma unroll
        for (int k = 0; k < 16; ++k) lds[SW(q + 256*p + 16*k)] = v[k];
    }
    __syncthreads();
    #pragma unroll
    for (int r = 0; r < 16; ++r) v[r] = lds[SW(tid + 256*r)];
    dft16<SIGN>(v);
    __syncthreads();                       // lds reusable by caller
}

// ---------------- radix-8 core (mid, new) -----------------------------------
// 8-point DFT: even/odd DFT4 + w8^k combine. Same dft4 pattern as dft16.
template<int SIGN>
__device__ __forceinline__ void dft8(float2 v[8]) {
    const float sgn = (float)SIGN;
    const float H2 = 0.707106781186548f;
    float2 a0 = v[0], a1 = v[2], a2 = v[4], a3 = v[6];
    float2 b0 = cadd(a0,a2), b1 = csub(a0,a2), b2 = cadd(a1,a3), b3 = csub(a1,a3);
    float2 ib3 = make_float2(-sgn*b3.y, sgn*b3.x);
    float2 E0 = cadd(b0,b2), E2 = csub(b0,b2), E1 = cadd(b1,ib3), E3 = csub(b1,ib3);
    a0 = v[1]; a1 = v[3]; a2 = v[5]; a3 = v[7];
    b0 = cadd(a0,a2); b1 = csub(a0,a2); b2 = cadd(a1,a3); b3 = csub(a1,a3);
    ib3 = make_float2(-sgn*b3.y, sgn*b3.x);
    float2 O0 = cadd(b0,b2), O2 = csub(b0,b2), O1 = cadd(b1,ib3), O3 = csub(b1,ib3);
    const float2 w1 = make_float2( H2,  sgn*H2);      // w8^1
    const float2 w3 = make_float2(-H2,  sgn*H2);      // w8^3
    O1 = cmul(O1, w1);
    O2 = make_float2(-sgn*O2.y, sgn*O2.x);            // w8^2 = SIGN*i
    O3 = cmul(O3, w3);
    v[0] = cadd(E0,O0); v[4] = csub(E0,O0);
    v[1] = cadd(E1,O1); v[5] = csub(E1,O1);
    v[2] = cadd(E2,O2); v[6] = csub(E2,O2);
    v[3] = cadd(E3,O3); v[7] = csub(E3,O3);
}

// Paired twiddle: v[k] *= e^{i*k*ang} for both register sets, one sincos.
__device__ __forceinline__ void twiddle8_pair(float2 v0[8], float2 v1[8], float ang) {
    float sn, cs; __sincosf(ang, &sn, &cs);
    float2 w  = make_float2(cs, sn);
    float2 w2 = cmul(w, w);
    float2 to = w;   // odd powers
    float2 te = w2;  // even powers
    v0[1] = cmul(v0[1], to); v1[1] = cmul(v1[1], to);
    v0[2] = cmul(v0[2], te); v1[2] = cmul(v1[2], te);
    to = cmul(to, w2); v0[3] = cmul(v0[3], to); v1[3] = cmul(v1[3], to);
    te = cmul(te, w2); v0[4] = cmul(v0[4], te); v1[4] = cmul(v1[4], te);
    to = cmul(to, w2); v0[5] = cmul(v0[5], to); v1[5] = cmul(v1[5], to);
    te = cmul(te, w2); v0[6] = cmul(v0[6], te); v1[6] = cmul(v1[6], te);
    to = cmul(to, w2); v0[7] = cmul(v0[7], to); v1[7] = cmul(v1[7], to);
}

// Paired Stockham radix-8, 4 stages, 512 threads, two 32KB buffers.
// Input: v[r] = x[tid + 512r]. Output: v[k] = X[tid + 512k].
// Trailing barrier: lds reusable by caller on exit.
template<int SIGN>
__device__ void fft4096_r8_pair(float2 v0[8], float2 v1[8],
                                float2* lds0, float2* lds1, int tid) {
    // stage 1: dft8 over r (stride 512), twiddle W_N^{tid*k}
    dft8<SIGN>(v0); dft8<SIGN>(v1);
    twiddle8_pair(v0, v1, (float)SIGN * 2.0f * PI_F * (float)tid / 4096.0f);
    #pragma unroll
    for (int k = 0; k < 8; ++k) {
        const int a = SW(8*tid + k);
        lds0[a] = v0[k]; lds1[a] = v1[k];
    }
    __syncthreads();
    #pragma unroll
    for (int r = 0; r < 8; ++r) {
        const int a = SW(tid + 512*r);
        v0[r] = lds0[a]; v1[r] = lds1[a];
    }
    // stage 2: twiddle W_512^{(tid>>3)*k}
    dft8<SIGN>(v0); dft8<SIGN>(v1);
    twiddle8_pair(v0, v1, (float)SIGN * 2.0f * PI_F * (float)(tid >> 3) / 512.0f);
    __syncthreads();                       // in-place: all reads before writes
    {
        const int base = (tid & 7) + 64*(tid >> 3);
        #pragma unroll
        for (int k = 0; k < 8; ++k) {
            const int a = SW(base + 8*k);
            lds0[a] = v0[k]; lds1[a] = v1[k];
        }
    }
    __syncthreads();
    #pragma unroll
    for (int r = 0; r < 8; ++r) {
        const int a = SW(tid + 512*r);
        v0[r] = lds0[a]; v1[r] = lds1[a];
    }
    // stage 3: twiddle W_64^{(tid>>6)*k}
    dft8<SIGN>(v0); dft8<SIGN>(v1);
    twiddle8_pair(v0, v1, (float)SIGN * 2.0f * PI_F * (float)(tid >> 6) / 64.0f);
    __syncthreads();
    {
        const int base = (tid & 63) + 512*(tid >> 6);
        #pragma unroll
        for (int k = 0; k < 8; ++k) {
            const int a = SW(base + 64*k);
            lds0[a] = v0[k]; lds1[a] = v1[k];
        }
    }
    __syncthreads();
    #pragma unroll
    for (int r = 0; r < 8; ++r) {
        const int a = SW(tid + 512*r);
        v0[r] = lds0[a]; v1[r] = lds1[a];
    }
    // stage 4: final dft8, no twiddle
    dft8<SIGN>(v0); dft8<SIGN>(v1);
    __syncthreads();                       // lds reusable by caller
}

// ---- Kernel A: precompute. grid 224 x 256. (unchanged radix-16)
// bid 0..31: Hc pair rows (ONE fft of D.(h0 + i*h1), no unpack needed);
// bid 32..95: Gf rows; bid 96..223: Xf rows.
__global__ __launch_bounds__(NT, 2) void ldr_pre_k(
    const float* __restrict__ x, const float* __restrict__ G, const float* __restrict__ H,
    float2* __restrict__ Hc, float2* __restrict__ Gf, float2* __restrict__ Xf)
{
    __shared__ float2 lds[NFFT];
    const int tid = threadIdx.x;
    const int bid = blockIdx.x;
    float2 v[16];
    if (bid < 32) {
        // Hc[p] = fft(D.(H[2p] + i*H[2p+1])) = Hf[2p] + i*Hf[2p+1]
        const float* h0 = H + (size_t)(2*bid)     * NFFT;
        const float* h1 = H + (size_t)(2*bid + 1) * NFFT;
        float sn, cs; __sincosf(PI_F * (float)tid / (float)NFFT, &sn, &cs);
        const float2 dt = make_float2(cs, sn);
        #pragma unroll
        for (int k = 0; k < 16; ++k) {
            const int e = tid + 256*k;
            const float2 d = cmul(dt, make_float2(CP16[k], SP16[k]));  // e^{i*pi*e/N}
            v[k] = cmul(d, make_float2(h0[e], h1[e]));
        }
        fft4096_r16<-1>(v, lds, tid);
        float2* o = Hc + (size_t)bid * NFFT;
        #pragma unroll
        for (int k = 0; k < 16; ++k) o[tid + 256*k] = v[k];
    } else if (bid < 96) {
        const int row = bid - 32;
        const float* g = G + (size_t)row * NFFT;
        #pragma unroll
        for (int k = 0; k < 16; ++k) v[k] = make_float2(g[tid + 256*k], 0.0f);
        fft4096_r16<-1>(v, lds, tid);
        float2* o = Gf + (size_t)row * NFFT;
        #pragma unroll
        for (int k = 0; k < 16; ++k) o[tid + 256*k] = v[k];
    } else {
        const int row = bid - 96;
        const float* xp = x + (size_t)row * NFFT;
        float sn, cs; __sincosf(PI_F * (float)tid / (float)NFFT, &sn, &cs);
        const float2 dt = make_float2(cs, -sn);                        // conj(D) thread part
        #pragma unroll
        for (int k = 0; k < 16; ++k) {
            const int e = tid + 256*k;
            const float2 d = cmul(dt, make_float2(CP16[k], -SP16[k])); // e^{-i*pi*e/N}
            float xv = xp[e];
            v[k] = make_float2(d.x*xv, d.y*xv);
        }
        fft4096_r16<1>(v, lds, tid);
        const float invn = 1.0f / (float)NFFT;
        float2* o = Xf + (size_t)row * NFFT;
        #pragma unroll
        for (int k = 0; k < 16; ++k) o[tid + 256*k] = make_float2(v[k].x*invn, v[k].y*invn);
    }
}

// ---- Kernel B: middle. grid 512 = ip(32) x bpair(16), 512 THREADS.
// Paired radix-8: b = 2bp and 2bp+1 simultaneously, v0[8]+v1[8] in regs,
// shared barriers/twiddles/hc/g loads. e = tid + 512k, k<8.
// Hermitian unpack: upper half = k in 4..7; Nyquist (e=2048) = v[4]@tid0.
__global__ __launch_bounds__(NTM, 2) void ldr_mid_k(
    const float2* __restrict__ Hc, const float2* __restrict__ Xf,
    const float2* __restrict__ Gf, __half2* __restrict__ Ph)
{
    __shared__ float2 lds0[NFFT];
    __shared__ float2 lds1[NFFT];
    const int tid = threadIdx.x;
    const int bid = blockIdx.x;         // [0,512)
    const int bp  = bid & 15;           // batch pair index -> b = 2bp, 2bp+1
    const int ip  = bid >> 4;           // ij*2 + pr, [0,32)
    const int pr  = ip & 1;
    const int ij  = ip >> 1;
    const int i   = ij >> 2;            // COUT = 4
    const int j   = ij & 3;
    const int r0  = ij*RANK + 2*pr;     // G rows s0 = r0, s1 = r0+1
    const int b0  = 2*bp;
    const float2* hc = Hc + (size_t)ip * NFFT;
    const float2* x0 = Xf + (size_t)(i*BATCH + b0) * NFFT;
    const float2* x1 = x0 + NFFT;       // b0+1: adjacent row
    const float2* g0 = Gf + (size_t)r0 * NFFT;
    const float2* g1 = g0 + NFFT;
    const int u = i*2 + pr;             // plane in [0,8)

    float2 v0[8], v1[8];
    #pragma unroll
    for (int k = 0; k < 8; ++k) {
        const int e = tid + NTM*k;
        const float2 h = hc[e];         // loaded ONCE for both products
        v0[k] = cmul(h, x0[e]);
        v1[k] = cmul(h, x1[e]);
    }
    fft4096_r8_pair<-1>(v0, v1, lds0, lds1, tid);
    {
        // D_e = e^{i*pi*(tid+512k)/4096} = e^{i*pi*tid/4096} * e^{i*pi*k/8}
        float sn, cs; __sincosf(PI_F * (float)tid / (float)NFFT, &sn, &cs);
        const float2 dt = make_float2(cs, sn);
        #pragma unroll
        for (int k = 0; k < 8; ++k) {
            const float2 d = cmul(dt, make_float2(CP8[k], SP8[k]));
            v0[k] = cmul(v0[k], d);
            v1[k] = cmul(v1[k], d);
        }
    }
    fft4096_r8_pair<-1>(v0, v1, lds0, lds1, tid);  // Z = fft(t0)+i*fft(t1)

    // Stage upper halves (e >= 2048: k = 4..7) for mirror access.
    #pragma unroll
    for (int k = 4; k < 8; ++k) {
        const int a = SW(tid + NTM*k);
        lds0[a] = v0[k]; lds1[a] = v1[k];
    }
    __syncthreads();

    __half2* prow0 = Ph + (size_t)((u*COUT + j)*BATCH + b0) * (NFFT/2);
    __half2* prow1 = prow0 + (NFFT/2);
    #pragma unroll
    for (int k = 0; k < 4; ++k) {
        const int e = tid + NTM*k;
        const float2 g0e = g0[e], g1e = g1[e];   // loaded ONCE for both
        // product 0
        {
            const float2 Zk = v0[k];
            float2 Zm;
            if (e == 0) Zm = Zk;
            else        Zm = lds0[SW(4096 - e)];
            const float2 V1 = make_float2(0.5f*(Zk.x + Zm.x), 0.5f*(Zk.y - Zm.y));
            const float2 V2 = make_float2(0.5f*(Zk.y + Zm.y), 0.5f*(Zm.x - Zk.x));
            float2 Y = cadd(cmul(g0e, V1), cmul(g1e, V2));
            if (k == 0 && tid == 0) {
                const float2 Zn = v0[4];                 // element 2048 (Nyquist)
                const float Ynyq = g0[2048].x * Zn.x + g1[2048].x * Zn.y;
                Y = make_float2(Y.x, Ynyq);              // pack DC.x / Nyq.x
            }
            prow0[e] = __floats2half2_rn(Y.x, Y.y);
        }
        // product 1
        {
            const float2 Zk = v1[k];
            float2 Zm;
            if (e == 0) Zm = Zk;
            else        Zm = lds1[SW(4096 - e)];
            const float2 V1 = make_float2(0.5f*(Zk.x + Zm.x), 0.5f*(Zk.y - Zm.y));
            const float2 V2 = make_float2(0.5f*(Zk.y + Zm.y), 0.5f*(Zm.x - Zk.x));
            float2 Y = cadd(cmul(g0e, V1), cmul(g1e, V2));
            if (k == 0 && tid == 0) {
                const float2 Zn = v1[4];
                const float Ynyq = g0[2048].x * Zn.x + g1[2048].x * Zn.y;
                Y = make_float2(Y.x, Ynyq);
            }
            prow1[e] = __floats2half2_rn(Y.x, Y.y);
        }
    }
}

// ---- Kernel C: final (R11 shape, unchanged). grid 128 = (j,b). Sum 8 fp16
// half-rows via int4 loads, conjugate-mirror upper half, one inverse FFT.
__global__ __launch_bounds__(NT, 2) void ldr_fin_k(
    const __half2* __restrict__ Ph, float* __restrict__ out)
{
    __shared__ float2 lds[NFFT];
    __shared__ float2 sh[NFFT/2];      // summed half-spectrum (packed elem 0)
    const int tid = threadIdx.x;
    const int bid = blockIdx.x;        // j*BATCH + b
    const int b = bid & (BATCH - 1);
    const int j = bid >> 5;

    float2 a[8];
    #pragma unroll
    for (int k = 0; k < 8; ++k) a[k] = make_float2(0.f, 0.f);
    #pragma unroll
    for (int u = 0; u < 8; ++u) {
        const int4* row4 = (const int4*)(Ph + (size_t)((u*COUT + j)*BATCH + b) * (NFFT/2));
        #pragma unroll
        for (int c = 0; c < 2; ++c) {
            const int4 w = row4[tid + 256*c];
            const int ww[4] = { w.x, w.y, w.z, w.w };
            #pragma unroll
            for (int r = 0; r < 4; ++r) {
                __half2 h = *(const __half2*)&ww[r];
                float2 f = __half22float2(h);
                a[c*4+r] = cadd(a[c*4+r], f);
            }
        }
    }
    float4* sh4 = (float4*)sh;
    #pragma unroll
    for (int c = 0; c < 2; ++c) {
        sh4[2*(tid + 256*c) + 0] = make_float4(a[c*4+0].x, a[c*4+0].y, a[c*4+1].x, a[c*4+1].y);
        sh4[2*(tid + 256*c) + 1] = make_float4(a[c*4+2].x, a[c*4+2].y, a[c*4+3].x, a[c*4+3].y);
    }
    __syncthreads();

    const float dc  = sh[0].x;
    const float nyq = sh[0].y;
    float2 v[16];
    #pragma unroll
    for (int k = 0; k < 8; ++k) v[k] = sh[tid + 256*k];
    if (tid == 0) v[0] = make_float2(dc, 0.0f);
    #pragma unroll
    for (int k = 8; k < 16; ++k) {
        const int m = 4096 - (tid + 256*k);          // mirror index in [1,2048]
        if (m == 2048) {                              // only tid==0, k==8
            v[k] = make_float2(nyq, 0.0f);
        } else {
            float2 c = sh[m];
            v[k] = make_float2(c.x, -c.y);            // conj
        }
    }
    // no barrier needed: fft writes lds[], sh[] untouched
    fft4096_r16<1>(v, lds, tid);
    const float invn = 1.0f / (float)NFFT;
    float* orow = out + (size_t)bid * NFFT;
    #pragma unroll
    for (int k = 0; k < 16; ++k) orow[tid + 256*k] = v[k].x * invn;
}

extern "C" void kernel_launch(void* const* d_in, const int* in_sizes, int n_in,
                              void* d_out, int out_size, void* d_ws, size_t ws_size,
                              hipStream_t stream) {
    const float* x = (const float*)d_in[0];   // (CIN, B, N)
    const float* G = (const float*)d_in[1];   // (CIN, COUT, R, N)
    const float* H = (const float*)d_in[2];   // (CIN, COUT, R, N)
    float* out = (float*)d_out;               // (COUT, B, N)

    float2*  Hc = (float2*)d_ws;                    // 32 packed pair rows (1 MB)
    float2*  Gf = Hc + (size_t)32 * NFFT;           // 64 rows (2 MB)
    float2*  Xf = Gf + (size_t)64 * NFFT;           // 128 rows (4 MB)
    __half2* Ph = (__half2*)(Xf + (size_t)128 * NFFT); // 1024 half-rows x 2048 h2 (8 MB)

    ldr_pre_k<<<224, NT, 0, stream>>>(x, G, H, Hc, Gf, Xf);
    ldr_mid_k<<<512, NTM, 0, stream>>>(Hc, Xf, Gf, Ph);  // 512 = ip(32) x bpair(16)
    ldr_fin_k<<<COUT * BATCH, NT, 0, stream>>>(Ph, out);
}